// Round 1
// baseline (583.579 us; speedup 1.0000x reference)
//
#include <hip/hip_runtime.h>

// Problem: h[t] = a[t]*h[t-1] + b[t] along axis S of (B,S,D,N) = (2,2048,1024,16), fp32.
// 32768 independent chains (one per (b,d,n)), scan stride = D*N elements.

constexpr int S_LEN        = 2048;
constexpr int DN           = 1024 * 16;          // 16384 chains per batch
constexpr long BATCH_STRIDE = (long)S_LEN * DN;  // elements per batch
constexpr int NCHAIN       = 2 * DN;             // 32768 total chains
constexpr int U            = 16;                 // prefetch depth (steps)

__global__ __launch_bounds__(64) void scan_chain_kernel(
    const float* __restrict__ a,
    const float* __restrict__ b,
    float* __restrict__ out)
{
    const int m  = blockIdx.x * 64 + threadIdx.x;   // chain id, 0..32767
    const int bi = m >> 14;                          // m / DN
    const int dn = m & (DN - 1);                     // m % DN
    const size_t base = (size_t)bi * BATCH_STRIDE + dn;

    const float* __restrict__ ap = a + base;
    const float* __restrict__ bp = b + base;
    float* __restrict__ op = out + base;

    float abuf[U], bbuf[U];
    #pragma unroll
    for (int u = 0; u < U; ++u) {
        abuf[u] = ap[(size_t)u * DN];
        bbuf[u] = bp[(size_t)u * DN];
    }

    float h = 0.0f;
    for (int s0 = 0; s0 < S_LEN; s0 += U) {
        // Prefetch next batch of U steps (independent of the fma chain).
        float anxt[U], bnxt[U];
        const int nxt = s0 + U;
        if (nxt < S_LEN) {
            const float* __restrict__ ap2 = ap + (size_t)nxt * DN;
            const float* __restrict__ bp2 = bp + (size_t)nxt * DN;
            #pragma unroll
            for (int u = 0; u < U; ++u) {
                anxt[u] = ap2[(size_t)u * DN];
                bnxt[u] = bp2[(size_t)u * DN];
            }
        }

        // Serial recurrence over the current batch + coalesced stores.
        float* __restrict__ op2 = op + (size_t)s0 * DN;
        #pragma unroll
        for (int u = 0; u < U; ++u) {
            h = fmaf(abuf[u], h, bbuf[u]);
            op2[(size_t)u * DN] = h;
        }

        // Rotate buffers (last iteration copies dead values; never read).
        #pragma unroll
        for (int u = 0; u < U; ++u) {
            abuf[u] = anxt[u];
            bbuf[u] = bnxt[u];
        }
    }
}

extern "C" void kernel_launch(void* const* d_in, const int* in_sizes, int n_in,
                              void* d_out, int out_size, void* d_ws, size_t ws_size,
                              hipStream_t stream) {
    const float* a = (const float*)d_in[0];
    const float* b = (const float*)d_in[1];
    float* out = (float*)d_out;

    dim3 grid(NCHAIN / 64);   // 512 blocks
    dim3 block(64);           // 1 wave each -> 2 waves/CU across 256 CUs
    scan_chain_kernel<<<grid, block, 0, stream>>>(a, b, out);
}